// Round 1
// baseline (255.323 us; speedup 1.0000x reference)
//
#include <hip/hip_runtime.h>
#include <hip/hip_bf16.h>

// MFVIConstituency: B=16, S=128, MAX_ITER=3.
// q_new[b,i,j] = s_span[b,i,j] + sum_k sigmoid(q[b,i,k]) * sp[b,i,j,k]
// sp[b,i,j,k]  = s_pair[b,i,j,k] * ( mask[b,i,j] & (k!=min(i,j)) & (k!=max(i,j))
//                                     & (mask[b,j,k]|mask[b,k,j]) )
// Recurrence is local to (b,i): one block per (b,i) row, sp slice staged in LDS once.

#define S 128
#define SP_STRIDE 129   // +1 pad: matvec bank = (j+k)%32 -> 2-way (free)
#define MB_STRIDE 132   // mask byte tile stride: transposed reads conflict-free

// LDS layout (dynamic, 70656 B total):
//   [0      ) float sp[128*129]        = 66048 B  (phase 0-2: mask bytes mb[128*132]=16896 B, unioned)
//   [66048  ) uint  spanw[128*4]       = 2048  B  (bit k of row j: mask[b,j,k]|mask[b,k,j])
//   [68096  ) float sspan[128]
//   [68608  ) float qrow [128]
//   [69120  ) float prow [128]
//   [69632  ) float partial[256]
#define SMEM_BYTES 70656

__global__ __launch_bounds__(256, 2) void mfvi_kernel(
    const float* __restrict__ s_span,
    const float* __restrict__ s_pair,
    const int*   __restrict__ mask,    // jnp.bool_ -> int32 per harness convention
    float* __restrict__ out)
{
    extern __shared__ char smem[];
    float*         sp      = (float*)smem;
    unsigned char* mb      = (unsigned char*)smem;            // valid phases 0-2 only
    unsigned int*  spanw   = (unsigned int*)(smem + 66048);
    float*         sspan   = (float*)(smem + 68096);
    float*         qrow    = (float*)(smem + 68608);
    float*         prow    = (float*)(smem + 69120);
    float*         partial = (float*)(smem + 69632);

    const int t  = threadIdx.x;
    const int bi = blockIdx.x;            // b*128 + i
    const int i  = bi & (S - 1);
    const long long tile_off = (long long)bi * (S * S);
    const long long mask_off = (long long)(bi >> 7) * (S * S);

    // ---- phase 0: stage mask[b] (int32) as bytes into mb, padded stride ----
    {
        const int* mrow = mask + mask_off;
        #pragma unroll
        for (int s = 0; s < 16; ++s) {
            int f4 = t + 256 * s;               // int4 index 0..4095
            int j  = f4 >> 5;                   // (4*f4)/128
            int k0 = (f4 & 31) * 4;
            int4 v = *(const int4*)(mrow + f4 * 4);
            unsigned int packed = (v.x ? 1u : 0u)
                                | ((v.y ? 1u : 0u) << 8)
                                | ((v.z ? 1u : 0u) << 16)
                                | ((v.w ? 1u : 0u) << 24);
            *(unsigned int*)(mb + j * MB_STRIDE + k0) = packed;
        }
    }
    __syncthreads();

    // ---- phase 1: pack mask[b,i,j] bits for this thread's 16 j's ----
    unsigned int m_i_pack = 0;
    #pragma unroll
    for (int s = 0; s < 16; ++s) {
        int j = (t >> 5) + 8 * s;
        m_i_pack |= (mb[i * MB_STRIDE + j] ? 1u : 0u) << s;
    }

    // ---- phase 2: span bits span[j][k] = m[j][k] | m[k][j], via wave ballot ----
    {
        int wave = t >> 6, lane = t & 63;
        for (int task = wave * 64; task < wave * 64 + 64; ++task) {
            int j = task >> 1, w = task & 1;
            int k = w * 64 + lane;
            bool sbit = (mb[j * MB_STRIDE + k] | mb[k * MB_STRIDE + j]) != 0;
            unsigned long long bal = __ballot(sbit);
            if (lane == 0)  spanw[j * 4 + w * 2 + 0] = (unsigned int)bal;
            if (lane == 32) spanw[j * 4 + w * 2 + 1] = (unsigned int)(bal >> 32);
        }
    }
    __syncthreads();   // mb dead after this point

    // ---- phase 3: stage masked s_pair slice into sp (overwrites mb region) ----
    {
        const float* tile = s_pair + tile_off;
        #pragma unroll
        for (int s = 0; s < 16; ++s) {
            int j  = (t >> 5) + 8 * s;
            int k0 = (t & 31) * 4;
            float4 v = *(const float4*)(tile + j * S + k0);
            unsigned int mi = (m_i_pack >> s) & 1u;
            unsigned int sw = spanw[j * 4 + (k0 >> 5)];
            int lo = min(i, j), hi = max(i, j);
            float r0 = 0.f, r1 = 0.f, r2 = 0.f, r3 = 0.f;
            if (mi) {
                int b0 = (k0 & 31);
                if (((sw >> (b0 + 0)) & 1u) && (k0 + 0 != lo) && (k0 + 0 != hi)) r0 = v.x;
                if (((sw >> (b0 + 1)) & 1u) && (k0 + 1 != lo) && (k0 + 1 != hi)) r1 = v.y;
                if (((sw >> (b0 + 2)) & 1u) && (k0 + 2 != lo) && (k0 + 2 != hi)) r2 = v.z;
                if (((sw >> (b0 + 3)) & 1u) && (k0 + 3 != lo) && (k0 + 3 != hi)) r3 = v.w;
            }
            int base = j * SP_STRIDE + k0;
            sp[base + 0] = r0;
            sp[base + 1] = r1;
            sp[base + 2] = r2;
            sp[base + 3] = r3;
        }
        if (t < S) {
            float sv = s_span[(long long)bi * S + t];
            sspan[t] = sv;
            qrow[t]  = sv;
        }
    }
    __syncthreads();

    // ---- phase 4: three MFVI iterations, all in LDS ----
    for (int it = 0; it < 3; ++it) {
        if (t < S) prow[t] = 1.0f / (1.0f + __expf(-qrow[t]));
        __syncthreads();
        {
            int j = t & (S - 1), h = t >> 7;          // 2 threads per output j, 64 k each
            const float* sprow = sp + j * SP_STRIDE + h * 64;
            const float* pv    = prow + h * 64;       // wave-uniform address -> broadcast
            float acc = 0.f;
            #pragma unroll
            for (int kk = 0; kk < 64; ++kk) acc += pv[kk] * sprow[kk];
            partial[t] = acc;
        }
        __syncthreads();
        if (t < S) qrow[t] = sspan[t] + partial[t] + partial[t + 128];
        __syncthreads();
    }
    if (t < S) out[(long long)bi * S + t] = 1.0f / (1.0f + __expf(-qrow[t]));
}

extern "C" void kernel_launch(void* const* d_in, const int* in_sizes, int n_in,
                              void* d_out, int out_size, void* d_ws, size_t ws_size,
                              hipStream_t stream) {
    const float* s_span = (const float*)d_in[0];
    const float* s_pair = (const float*)d_in[1];
    const int*   mask   = (const int*)d_in[2];
    float*       out    = (float*)d_out;

    int num_rows = in_sizes[0] / S;   // B*S = 2048 blocks, one per (b,i)

    // >64KB dynamic LDS needs the opt-in attribute (host-side, idempotent,
    // graph-capture safe: not a stream op).
    (void)hipFuncSetAttribute((const void*)mfvi_kernel,
                              hipFuncAttributeMaxDynamicSharedMemorySize,
                              SMEM_BYTES);

    mfvi_kernel<<<num_rows, 256, SMEM_BYTES, stream>>>(s_span, s_pair, mask, out);
}

// Round 2
// 208.340 us; speedup vs baseline: 1.2255x; 1.2255x over previous
//
#include <hip/hip_runtime.h>
#include <hip/hip_bf16.h>

// MFVIConstituency: B=16, S=128, MAX_ITER=3.
// q_new[b,i,j] = s_span[b,i,j] + sum_k sigmoid(q[b,i,k]) * sp[b,i,j,k]
// sp[b,i,j,k]  = s_pair[b,i,j,k] * ( mask[b,i,j] & (k!=min(i,j)) & (k!=max(i,j))
//                                     & (mask[b,j,k]|mask[b,k,j]) )
//
// Round-2 restructure:
//  - pack_masks (16 blocks): per-b span/row bitmasks -> d_ws (64 KB), removing
//    the per-(b,i) 64 KB mask reads + serial ballot loop of round 1.
//  - mfvi_main: one block per (b,i); masked s_pair slice lives in REGISTERS
//    (16 float4/thread), LDS ~20 KB -> 4 blocks/CU instead of 2.

#define S 128
#define MB_STRIDE 132     // mask byte tile: transposed byte reads conflict-free
#define PART_STRIDE 33    // partial-sum tile: writes (c+lane)%32, reads (t+c)%32 -> conflict-free

// ---------------- pre-pack: span & row bitmasks per batch ----------------
__global__ __launch_bounds__(256, 2) void pack_masks(
    const int* __restrict__ mask, unsigned* __restrict__ spanw,
    unsigned* __restrict__ miw)
{
    __shared__ unsigned char mb[S * MB_STRIDE];   // 16896 B
    const int t = threadIdx.x, b = blockIdx.x;
    const int* mrow = mask + (long long)b * (S * S);
    #pragma unroll
    for (int s2 = 0; s2 < 16; ++s2) {
        int f4 = t + 256 * s2;            // int4 index 0..4095
        int j  = f4 >> 5;
        int k0 = (f4 & 31) * 4;
        int4 v = *(const int4*)(mrow + f4 * 4);
        unsigned packed = (v.x ? 1u : 0u)
                        | ((v.y ? 1u : 0u) << 8)
                        | ((v.z ? 1u : 0u) << 16)
                        | ((v.w ? 1u : 0u) << 24);
        *(unsigned*)(mb + j * MB_STRIDE + k0) = packed;
    }
    __syncthreads();
    #pragma unroll
    for (int r = 0; r < 2; ++r) {
        int task = t * 2 + r;             // 0..511 = (j, w)
        int j = task >> 2, w = task & 3;
        unsigned sbits = 0, mbits = 0;
        #pragma unroll
        for (int c = 0; c < 32; ++c) {
            int k = w * 32 + c;
            unsigned mjk = mb[j * MB_STRIDE + k];
            unsigned mkj = mb[k * MB_STRIDE + j];
            sbits |= ((mjk | mkj) ? 1u : 0u) << c;
            mbits |= (mjk ? 1u : 0u) << c;
        }
        spanw[(b * S + j) * 4 + w] = sbits;   // bit k of row j: mask[b,j,k]|mask[b,k,j]
        miw  [(b * S + j) * 4 + w] = mbits;   // bit k of row j: mask[b,j,k]
    }
}

// ---------------- main: one block per (b,i), sp slice in registers ----------------
__global__ __launch_bounds__(256, 4) void mfvi_main(
    const float* __restrict__ s_span,
    const float* __restrict__ s_pair,
    const unsigned* __restrict__ spanw,
    const unsigned* __restrict__ miw,
    float* __restrict__ out)
{
    __shared__ float    part[S * PART_STRIDE];   // 16896 B
    __shared__ unsigned sw_l[S * 4];             // 2048 B
    __shared__ float    prow[S];                 // 512 B
    __shared__ unsigned miw_l[4];

    const int t  = threadIdx.x;
    const int bi = blockIdx.x;        // b*128 + i
    const int i  = bi & (S - 1);
    const int b  = bi >> 7;
    const int row0 = t >> 5;          // 0..7
    const int k0   = (t & 31) * 4;    // 0..124
    const float* tile = s_pair + (long long)bi * (S * S);

    // s_pair slice into registers: thread owns rows j = row0+8s, k in [k0,k0+4).
    // Per instruction s, the wave covers 2 full rows = 1 KB contiguous.
    float4 v[16];
    #pragma unroll
    for (int s = 0; s < 16; ++s)
        v[s] = *(const float4*)(tile + (row0 + 8 * s) * S + k0);

    if (t < S)  *(uint4*)&sw_l[t * 4] = *(const uint4*)&spanw[(b * S + t) * 4];
    if (t < 4)  miw_l[t] = miw[(b * S + i) * 4 + t];
    float sv = 0.f;
    if (t < S) {
        sv = s_span[(long long)bi * S + t];
        prow[t] = 1.0f / (1.0f + __expf(-sv));     // p for iteration 0
    }
    __syncthreads();

    // apply the combined mask into the register tile
    #pragma unroll
    for (int s = 0; s < 16; ++s) {
        int j = row0 + 8 * s;
        unsigned sw = sw_l[j * 4 + (k0 >> 5)];
        bool mi = (miw_l[j >> 5] >> (j & 31)) & 1u;
        int lo = min(i, j), hi = max(i, j);
        int bb = k0 & 31;
        if (!(mi && ((sw >> (bb + 0)) & 1u) && (k0 + 0) != lo && (k0 + 0) != hi)) v[s].x = 0.f;
        if (!(mi && ((sw >> (bb + 1)) & 1u) && (k0 + 1) != lo && (k0 + 1) != hi)) v[s].y = 0.f;
        if (!(mi && ((sw >> (bb + 2)) & 1u) && (k0 + 2) != lo && (k0 + 2) != hi)) v[s].z = 0.f;
        if (!(mi && ((sw >> (bb + 3)) & 1u) && (k0 + 3) != lo && (k0 + 3) != hi)) v[s].w = 0.f;
    }

    const int pcol = t & 31;
    for (int it = 0; it < 3; ++it) {
        float4 p = *(const float4*)&prow[k0];    // ds_read_b128, 2-way broadcast (free)
        #pragma unroll
        for (int s = 0; s < 16; ++s) {
            int j = row0 + 8 * s;
            float acc = v[s].x * p.x + v[s].y * p.y + v[s].z * p.z + v[s].w * p.w;
            part[j * PART_STRIDE + pcol] = acc;
        }
        __syncthreads();
        if (t < S) {
            float sum = 0.f;
            #pragma unroll
            for (int c = 0; c < 32; ++c) sum += part[t * PART_STRIDE + c];
            float q = sv + sum;
            if (it < 2) prow[t] = 1.0f / (1.0f + __expf(-q));
            else        out[(long long)bi * S + t] = 1.0f / (1.0f + __expf(-q));
        }
        if (it < 2) __syncthreads();
    }
}

extern "C" void kernel_launch(void* const* d_in, const int* in_sizes, int n_in,
                              void* d_out, int out_size, void* d_ws, size_t ws_size,
                              hipStream_t stream) {
    const float* s_span = (const float*)d_in[0];
    const float* s_pair = (const float*)d_in[1];
    const int*   mask   = (const int*)d_in[2];
    float*       out    = (float*)d_out;

    int num_rows = in_sizes[0] / S;        // B*S = 2048
    int B        = in_sizes[2] / (S * S);  // 16

    unsigned* ws_span = (unsigned*)d_ws;                    // B*S*4 uints = 32 KB
    unsigned* ws_mi   = ws_span + (size_t)B * S * 4;        // +32 KB

    pack_masks<<<B, 256, 0, stream>>>(mask, ws_span, ws_mi);
    mfvi_main<<<num_rows, 256, 0, stream>>>(s_span, s_pair, ws_span, ws_mi, out);
}

// Round 3
// 191.188 us; speedup vs baseline: 1.3355x; 1.0897x over previous
//
#include <hip/hip_runtime.h>
#include <hip/hip_bf16.h>

// MFVIConstituency: B=16, S=128, MAX_ITER=3.
// q_new[b,i,j] = s_span[b,i,j] + sum_k sigmoid(q[b,i,k]) * sp[b,i,j,k]
// sp[b,i,j,k]  = s_pair[b,i,j,k] * ( mask[b,i,j] & (k!=min(i,j)) & (k!=max(i,j))
//                                     & (mask[b,j,k]|mask[b,k,j]) )
//
// Round-3: active-row compaction. If mask[b,i,j]==0 the whole j-row of the
// (b,i) tile is dead: skip its loads, FMAs, and reduction (~50% of all work,
// including the dominant 128 MB s_pair stream -> ~64 MB).

#define S 128
#define MB_STRIDE 132     // mask byte tile: transposed byte reads conflict-free
#define PART_STRIDE 33    // partial tile: (idx+col)%32 banks -> conflict-free

static __device__ __forceinline__ float fsig(float x) {
    return __builtin_amdgcn_rcpf(1.0f + __expf(-x));
}

// ---------------- pre-pack: span & row bitmasks per batch ----------------
__global__ __launch_bounds__(256, 2) void pack_masks(
    const int* __restrict__ mask, unsigned* __restrict__ spanw,
    unsigned* __restrict__ miw)
{
    __shared__ unsigned char mb[S * MB_STRIDE];   // 16896 B
    const int t = threadIdx.x, b = blockIdx.x;
    const int* mrow = mask + (long long)b * (S * S);
    #pragma unroll
    for (int s2 = 0; s2 < 16; ++s2) {
        int f4 = t + 256 * s2;            // int4 index 0..4095
        int j  = f4 >> 5;
        int k0 = (f4 & 31) * 4;
        int4 v = *(const int4*)(mrow + f4 * 4);
        unsigned packed = (v.x ? 1u : 0u)
                        | ((v.y ? 1u : 0u) << 8)
                        | ((v.z ? 1u : 0u) << 16)
                        | ((v.w ? 1u : 0u) << 24);
        *(unsigned*)(mb + j * MB_STRIDE + k0) = packed;
    }
    __syncthreads();
    #pragma unroll
    for (int r = 0; r < 2; ++r) {
        int task = t * 2 + r;             // 0..511 = (j, w)
        int j = task >> 2, w = task & 3;
        unsigned sbits = 0, mbits = 0;
        #pragma unroll
        for (int c = 0; c < 32; ++c) {
            int k = w * 32 + c;
            unsigned mjk = mb[j * MB_STRIDE + k];
            unsigned mkj = mb[k * MB_STRIDE + j];
            sbits |= ((mjk | mkj) ? 1u : 0u) << c;
            mbits |= (mjk ? 1u : 0u) << c;
        }
        spanw[(b * S + j) * 4 + w] = sbits;   // bit k: mask[b,j,k]|mask[b,k,j]
        miw  [(b * S + j) * 4 + w] = mbits;   // bit k: mask[b,j,k]
    }
}

// ---------------- main: one block per (b,i), active rows only ----------------
__global__ __launch_bounds__(256, 4) void mfvi_main(
    const float* __restrict__ s_span,
    const float* __restrict__ s_pair,
    const unsigned* __restrict__ spanw,
    const unsigned* __restrict__ miw,
    float* __restrict__ out)
{
    __shared__ float         part[S * PART_STRIDE];   // 16896 B, indexed by COMPACT idx
    __shared__ unsigned      sw_l[S * 4];             // 2048 B
    __shared__ float         prow[S];                 // sigmoid(q) per row
    __shared__ float         qsv [S];                 // s_span row
    __shared__ unsigned char act [S];                 // compact active-j list
    __shared__ int           nact_s;

    const int t  = threadIdx.x;
    const int bi = blockIdx.x;        // b*128 + i
    const int i  = bi & (S - 1);
    const int b  = bi >> 7;
    const int row0 = t >> 5;          // 0..7
    const int c4   = (t & 31) * 4;    // k base 0..124
    const float* tile = s_pair + (long long)bi * (S * S);

    // ---- init: span words, s_span, initial p, active-list compaction ----
    if (t < S) *(uint4*)&sw_l[t * 4] = *(const uint4*)&spanw[(b * S + t) * 4];
    if (t < S) {
        float sv = s_span[(long long)bi * S + t];
        qsv[t]  = sv;
        prow[t] = fsig(sv);           // iteration-0 p for EVERY row; final for inactive
    }
    if (t < 64) {                     // wave 0 compacts j=0..127 in two ballots
        unsigned w0 = miw[(b * S + i) * 4 + (t >> 5)];
        bool a0 = (w0 >> (t & 31)) & 1u;
        unsigned long long b0 = __ballot(a0);
        int p0 = __popcll(b0 & ((1ull << t) - 1ull));
        if (a0) act[p0] = (unsigned char)t;
        int n0 = __popcll(b0);
        int j1 = t + 64;
        unsigned w1 = miw[(b * S + i) * 4 + (j1 >> 5)];
        bool a1 = (w1 >> (j1 & 31)) & 1u;
        unsigned long long b1 = __ballot(a1);
        int p1 = n0 + __popcll(b1 & ((1ull << t) - 1ull));
        if (a1) act[p1] = (unsigned char)j1;
        if (t == 0) nact_s = n0 + __popcll(b1);
    }
    __syncthreads();
    const int nact = nact_s;

    // inactive rows: q stays s_span forever -> output now (overlaps loads)
    if (t < S) {
        bool mine = (miw[(b * S + i) * 4 + (t >> 5)] >> (t & 31)) & 1u;
        if (!mine) out[(long long)bi * S + t] = prow[t];
    }

    // ---- load only active rows (compact idx = row0 + 8s) ----
    float4 v[16];
    #pragma unroll
    for (int s = 0; s < 16; ++s) {
        int idx = row0 + 8 * s;
        if (idx < nact) {
            int j = act[idx];
            v[s] = *(const float4*)(tile + j * S + c4);
        } else {
            v[s] = make_float4(0.f, 0.f, 0.f, 0.f);
        }
    }

    // ---- apply span & (k!=lo,hi) mask: sign-extend bit -> and ----
    #pragma unroll
    for (int s = 0; s < 16; ++s) {
        int idx = row0 + 8 * s;
        if (idx < nact) {
            int j = act[idx];
            unsigned cw = sw_l[j * 4 + (c4 >> 5)];
            int lo = i < j ? i : j, hi = i < j ? j : i;
            if ((lo >> 5) == (c4 >> 5)) cw &= ~(1u << (lo & 31));
            if ((hi >> 5) == (c4 >> 5)) cw &= ~(1u << (hi & 31));
            unsigned cs = cw >> (c4 & 31);      // bits 0..3 = this thread's 4 k's
            int m0 = ((int)(cs << 31)) >> 31;
            int m1 = ((int)(cs << 30)) >> 31;
            int m2 = ((int)(cs << 29)) >> 31;
            int m3 = ((int)(cs << 28)) >> 31;
            v[s].x = __int_as_float(__float_as_int(v[s].x) & m0);
            v[s].y = __int_as_float(__float_as_int(v[s].y) & m1);
            v[s].z = __int_as_float(__float_as_int(v[s].z) & m2);
            v[s].w = __int_as_float(__float_as_int(v[s].w) & m3);
        }
    }

    // ---- 3 MFVI iterations over active rows only ----
    const int pcol = t & 31;
    #pragma unroll
    for (int it = 0; it < 3; ++it) {
        float4 p = *(const float4*)&prow[c4];   // ds_read_b128, 2-way bcast (free)
        #pragma unroll
        for (int s = 0; s < 16; ++s) {
            int idx = row0 + 8 * s;
            if (idx < nact) {
                float acc = v[s].x * p.x + v[s].y * p.y + v[s].z * p.z + v[s].w * p.w;
                part[idx * PART_STRIDE + pcol] = acc;
            }
        }
        __syncthreads();
        if (t < nact) {                          // one thread per ACTIVE row
            int j = act[t];
            float sum = 0.f;
            #pragma unroll
            for (int c = 0; c < 32; ++c) sum += part[t * PART_STRIDE + c];
            float q = qsv[j] + sum;
            if (it < 2) prow[j] = fsig(q);
            else        out[(long long)bi * S + j] = fsig(q);
        }
        if (it < 2) __syncthreads();
    }
}

extern "C" void kernel_launch(void* const* d_in, const int* in_sizes, int n_in,
                              void* d_out, int out_size, void* d_ws, size_t ws_size,
                              hipStream_t stream) {
    const float* s_span = (const float*)d_in[0];
    const float* s_pair = (const float*)d_in[1];
    const int*   mask   = (const int*)d_in[2];
    float*       out    = (float*)d_out;

    int num_rows = in_sizes[0] / S;        // B*S = 2048
    int B        = in_sizes[2] / (S * S);  // 16

    unsigned* ws_span = (unsigned*)d_ws;                    // B*S*4 uints = 32 KB
    unsigned* ws_mi   = ws_span + (size_t)B * S * 4;        // +32 KB

    pack_masks<<<B, 256, 0, stream>>>(mask, ws_span, ws_mi);
    mfvi_main<<<num_rows, 256, 0, stream>>>(s_span, s_pair, ws_span, ws_mi, out);
}